// Round 1
// baseline (706.129 us; speedup 1.0000x reference)
//
#include <hip/hip_runtime.h>
#include <math.h>

#define BB 8
#define CC 512
#define KK 19
#define HWHW 16384
#define INV_HW (1.0f/16384.0f)

// -------- K1: mask = sigmoid(einsum('bchw,kc->bkhw', x, Wm) + bm) --------
// 512 blocks (b, 256-pixel chunk), 256 threads, 1 pixel/thread.
// Wm/bm indexed wave-uniformly -> s_load path (scalar cache), no LDS.
__global__ __launch_bounds__(256) void k_mask(const float* __restrict__ x,
                                              const float* __restrict__ Wm,
                                              const float* __restrict__ bm,
                                              float* __restrict__ mask) {
    const int blk = blockIdx.x;
    const int b = blk >> 6;
    const int p = ((blk & 63) << 8) + threadIdx.x;
    const float* xb = x + (size_t)b * CC * HWHW + p;

    float pm[KK];
#pragma unroll
    for (int k = 0; k < KK; ++k) pm[k] = 0.0f;

    for (int c = 0; c < CC; c += 4) {
        const float xv0 = xb[(size_t)(c + 0) * HWHW];
        const float xv1 = xb[(size_t)(c + 1) * HWHW];
        const float xv2 = xb[(size_t)(c + 2) * HWHW];
        const float xv3 = xb[(size_t)(c + 3) * HWHW];
#pragma unroll
        for (int k = 0; k < KK; ++k) {
            const float* wr = Wm + k * CC + c;   // uniform -> s_load
            pm[k] += wr[0] * xv0 + wr[1] * xv1 + wr[2] * xv2 + wr[3] * xv3;
        }
    }

    float* mb = mask + (size_t)b * KK * HWHW + p;
#pragma unroll
    for (int k = 0; k < KK; ++k) {
        const float t = pm[k] + bm[k];
        mb[(size_t)k * HWHW] = 1.0f / (1.0f + __expf(-t));
    }
}

// -------- K2: class_feat[b,k,c] = (1/hw) * sum_p mask[b,k,p] * x[b,c,p] --------
// 1024 blocks (b, c-quad). Each block accumulates its 19x4 outputs over all
// 16384 pixels in registers (76 acc), then block-reduces. No atomics.
__global__ __launch_bounds__(256) void k_classfeat(const float* __restrict__ x,
                                                   const float* __restrict__ mask,
                                                   float* __restrict__ cf) {
    const int blk = blockIdx.x;
    const int b = blk >> 7;               // /128
    const int c0 = (blk & 127) << 2;
    const float* xb = x + (size_t)b * CC * HWHW;
    const float* mb = mask + (size_t)b * KK * HWHW;

    float acc[KK][4];
#pragma unroll
    for (int k = 0; k < KK; ++k)
#pragma unroll
        for (int j = 0; j < 4; ++j) acc[k][j] = 0.0f;

    for (int i = 0; i < HWHW / 256; ++i) {
        const int p = (i << 8) + threadIdx.x;
        const float xv0 = xb[(size_t)(c0 + 0) * HWHW + p];
        const float xv1 = xb[(size_t)(c0 + 1) * HWHW + p];
        const float xv2 = xb[(size_t)(c0 + 2) * HWHW + p];
        const float xv3 = xb[(size_t)(c0 + 3) * HWHW + p];
#pragma unroll
        for (int k = 0; k < KK; ++k) {
            const float m = mb[(size_t)k * HWHW + p];
            acc[k][0] += m * xv0;
            acc[k][1] += m * xv1;
            acc[k][2] += m * xv2;
            acc[k][3] += m * xv3;
        }
    }

    __shared__ float red[4][KK * 4];
    const int wave = threadIdx.x >> 6;
    const int lane = threadIdx.x & 63;
#pragma unroll
    for (int k = 0; k < KK; ++k)
#pragma unroll
        for (int j = 0; j < 4; ++j) {
            float v = acc[k][j];
#pragma unroll
            for (int off = 32; off > 0; off >>= 1) v += __shfl_down(v, off, 64);
            if (lane == 0) red[wave][k * 4 + j] = v;
        }
    __syncthreads();
    if (threadIdx.x < KK * 4) {
        const float s = red[0][threadIdx.x] + red[1][threadIdx.x] +
                        red[2][threadIdx.x] + red[3][threadIdx.x];
        const int k = threadIdx.x >> 2;
        const int j = threadIdx.x & 3;
        cf[((size_t)b * KK + k) * CC + c0 + j] = s * INV_HW;
    }
}

// -------- K3: filters[b,k,o] = sum_c Wf[k,o,c]*cf[b,k,c] + bf[k,o] --------
// 2432 blocks (k, o-quad), 4 waves/block, one o per wave; lanes span c.
__global__ __launch_bounds__(256) void k_filters(const float* __restrict__ Wf,
                                                 const float* __restrict__ bf,
                                                 const float* __restrict__ cf,
                                                 float* __restrict__ fil) {
    const int blk = blockIdx.x;
    const int k = blk >> 7;                         // /128 -> 0..18
    const int o = ((blk & 127) << 2) + (threadIdx.x >> 6);
    const int lane = threadIdx.x & 63;
    const float* wrow = Wf + ((size_t)k * CC + o) * CC;

    float acc[BB];
#pragma unroll
    for (int b = 0; b < BB; ++b) acc[b] = 0.0f;

#pragma unroll
    for (int j = 0; j < CC / 64; ++j) {
        const int c = lane + (j << 6);
        const float wv = wrow[c];
#pragma unroll
        for (int b = 0; b < BB; ++b)
            acc[b] += wv * cf[((size_t)b * KK + k) * CC + c];
    }
#pragma unroll
    for (int b = 0; b < BB; ++b) {
#pragma unroll
        for (int off = 32; off > 0; off >>= 1)
            acc[b] += __shfl_down(acc[b], off, 64);
    }
    if (lane == 0) {
        const float bias = bf[k * CC + o];
#pragma unroll
        for (int b = 0; b < BB; ++b)
            fil[((size_t)b * KK + k) * CC + o] = acc[b] + bias;
    }
}

// -------- K4: pred[b,k,p] = sum_c filters[b,k,c]*x[b,c,p] --------
// Same structure as K1; filters indexed wave-uniformly -> s_load.
__global__ __launch_bounds__(256) void k_pred(const float* __restrict__ x,
                                              const float* __restrict__ fil,
                                              float* __restrict__ out) {
    const int blk = blockIdx.x;
    const int b = blk >> 6;
    const int p = ((blk & 63) << 8) + threadIdx.x;
    const float* xb = x + (size_t)b * CC * HWHW + p;
    const float* fb = fil + (size_t)b * KK * CC;    // uniform base

    float acc[KK];
#pragma unroll
    for (int k = 0; k < KK; ++k) acc[k] = 0.0f;

    for (int c = 0; c < CC; c += 4) {
        const float xv0 = xb[(size_t)(c + 0) * HWHW];
        const float xv1 = xb[(size_t)(c + 1) * HWHW];
        const float xv2 = xb[(size_t)(c + 2) * HWHW];
        const float xv3 = xb[(size_t)(c + 3) * HWHW];
#pragma unroll
        for (int k = 0; k < KK; ++k) {
            const float* fr = fb + k * CC + c;       // uniform -> s_load
            acc[k] += fr[0] * xv0 + fr[1] * xv1 + fr[2] * xv2 + fr[3] * xv3;
        }
    }

    float* ob = out + (size_t)b * KK * HWHW + p;
#pragma unroll
    for (int k = 0; k < KK; ++k) ob[(size_t)k * HWHW] = acc[k];
}

extern "C" void kernel_launch(void* const* d_in, const int* in_sizes, int n_in,
                              void* d_out, int out_size, void* d_ws, size_t ws_size,
                              hipStream_t stream) {
    const float* x  = (const float*)d_in[0];
    const float* Wm = (const float*)d_in[1];
    const float* bm = (const float*)d_in[2];
    const float* Wf = (const float*)d_in[3];
    const float* bf = (const float*)d_in[4];
    float* out = (float*)d_out;

    float* mask = (float*)d_ws;                               // B*K*HW floats
    float* cf   = mask + (size_t)BB * KK * HWHW;              // B*K*C floats
    float* fil  = cf   + (size_t)BB * KK * CC;                // B*K*C floats

    k_mask<<<512, 256, 0, stream>>>(x, Wm, bm, mask);
    k_classfeat<<<1024, 256, 0, stream>>>(x, mask, cf);
    k_filters<<<2432, 256, 0, stream>>>(Wf, bf, cf, fil);
    k_pred<<<512, 256, 0, stream>>>(x, fil, out);
}